// Round 2
// baseline (1234.725 us; speedup 1.0000x reference)
//
#include <hip/hip_runtime.h>
#include <stdint.h>

typedef __attribute__((ext_vector_type(8))) short short8;
typedef __attribute__((ext_vector_type(4))) float floatx4;

#define T_TOK 4096
#define D_DIM 1024
#define H_DIM 4096
#define E_NUM 8

static __device__ __forceinline__ ushort f2bf(float f) {
    uint32_t u = __float_as_uint(f);
    u += 0x7FFF + ((u >> 16) & 1);   // round-to-nearest-even
    return (ushort)(u >> 16);
}

static __device__ __forceinline__ uint4 pack8(float4 a, float4 b) {
    union { ushort u[8]; uint4 v; } r;
    r.u[0] = f2bf(a.x); r.u[1] = f2bf(a.y); r.u[2] = f2bf(a.z); r.u[3] = f2bf(a.w);
    r.u[4] = f2bf(b.x); r.u[5] = f2bf(b.y); r.u[6] = f2bf(b.z); r.u[7] = f2bf(b.w);
    return r.v;
}

// ---------------- Router: logits -> softmax -> top2 -> renorm (all f32) ------
__global__ __launch_bounds__(256) void router_kernel(
    const float* __restrict__ x, const float* __restrict__ rw,
    int* __restrict__ counts, int* __restrict__ topi, float* __restrict__ topw)
{
    __shared__ float rwS[E_NUM * D_DIM];             // 32 KB
    int tid = threadIdx.x;
    for (int i = tid; i < E_NUM * D_DIM / 4; i += 256)
        ((float4*)rwS)[i] = ((const float4*)rw)[i];
    __syncthreads();

    int wave = tid >> 6, lane = tid & 63;
    int t = blockIdx.x * 4 + wave;
    const float* xr = x + (size_t)t * D_DIM;

    float acc[E_NUM];
#pragma unroll
    for (int e = 0; e < E_NUM; e++) acc[e] = 0.f;

    // each lane handles 16 contiguous elements
    float xv[16];
#pragma unroll
    for (int j = 0; j < 4; j++)
        *(float4*)&xv[j * 4] = ((const float4*)xr)[lane * 4 + j];
#pragma unroll
    for (int j = 0; j < 16; j++) {
        int idx = lane * 16 + j;
#pragma unroll
        for (int e = 0; e < E_NUM; e++)
            acc[e] += xv[j] * rwS[e * D_DIM + idx];
    }
#pragma unroll
    for (int e = 0; e < E_NUM; e++)
        for (int off = 32; off > 0; off >>= 1)
            acc[e] += __shfl_xor(acc[e], off, 64);

    if (lane == 0) {
        float mx = acc[0];
        for (int e = 1; e < E_NUM; e++) mx = fmaxf(mx, acc[e]);
        float p[E_NUM];
        for (int e = 0; e < E_NUM; e++) p[e] = expf(acc[e] - mx);
        int i0 = 0;
        for (int e = 1; e < E_NUM; e++) if (p[e] > p[i0]) i0 = e;   // lowest-idx tie-break
        int i1 = (i0 == 0) ? 1 : 0;
        for (int e = 0; e < E_NUM; e++) if (e != i0 && p[e] > p[i1]) i1 = e;
        float w0 = p[i0], w1 = p[i1], sw = w0 + w1;
        w0 /= sw; w1 /= sw;
        topi[t * 2] = i0; topi[t * 2 + 1] = i1;
        topw[t * 2] = w0; topw[t * 2 + 1] = w1;
        atomicAdd(&counts[i0], 1);
        atomicAdd(&counts[i1], 1);
    }
}

__global__ void offsets_kernel(const int* __restrict__ counts,
                               int* __restrict__ offsets, int* __restrict__ cursors)
{
    if (threadIdx.x == 0 && blockIdx.x == 0) {
        int off = 0;
        for (int e = 0; e < E_NUM; e++) {
            offsets[e] = off; cursors[e] = off; off += counts[e];
        }
    }
}

__global__ __launch_bounds__(256) void assign_kernel(
    const int* __restrict__ topi, const float* __restrict__ topw,
    int* __restrict__ cursors, int* __restrict__ pair_token, float* __restrict__ pair_w)
{
    int t = blockIdx.x * 256 + threadIdx.x;
    if (t >= T_TOK) return;
    for (int k = 0; k < 2; k++) {
        int e = topi[t * 2 + k];
        int pos = atomicAdd(&cursors[e], 1);
        pair_token[pos] = t;
        pair_w[pos] = topw[t * 2 + k];
    }
}

// ---------------- FFN layer 1: h = gelu(x @ w1[e]^T + b1[e]) ----------------
// Grouped GEMM, 64x64 tile, BK=32, mfma 16x16x32 bf16; f32 global -> bf16 LDS.
__global__ __launch_bounds__(256) void ffn1_kernel(
    const float* __restrict__ x, const float* __restrict__ w1, const float* __restrict__ b1,
    const int* __restrict__ counts, const int* __restrict__ offsets,
    const int* __restrict__ pair_token, ushort* __restrict__ h)
{
    int e = blockIdx.z;
    int cnt = counts[e];
    int m0 = blockIdx.x * 64;
    if (m0 >= cnt) return;
    int off = offsets[e];
    int n0 = blockIdx.y * 64;

    __shared__ ushort As[64][40];   // +8 pad: kills bank conflicts on b128 frag reads
    __shared__ ushort Bs[64][40];

    int tid = threadIdx.x;
    int r = tid >> 2, cseg = (tid & 3) * 8;
    int gr = m0 + r; if (gr > cnt - 1) gr = cnt - 1;
    const float* arow = x + (size_t)pair_token[off + gr] * D_DIM + cseg;
    const float* brow = w1 + ((size_t)e * H_DIM + n0 + r) * D_DIM + cseg;

    int wave = tid >> 6, lane = tid & 63;
    int quad = lane >> 4, l16 = lane & 15;

    floatx4 acc[4] = {};
    const short8* aF = (const short8*)&As[wave * 16 + l16][quad * 8];

    for (int k0 = 0; k0 < D_DIM; k0 += 32) {
        float4 a0 = *(const float4*)(arow + k0);
        float4 a1 = *(const float4*)(arow + k0 + 4);
        float4 b0 = *(const float4*)(brow + k0);
        float4 b1v = *(const float4*)(brow + k0 + 4);
        __syncthreads();
        *(uint4*)&As[r][cseg] = pack8(a0, a1);
        *(uint4*)&Bs[r][cseg] = pack8(b0, b1v);
        __syncthreads();
        short8 af = *aF;
#pragma unroll
        for (int c = 0; c < 4; c++) {
            short8 bf = *(const short8*)&Bs[c * 16 + l16][quad * 8];
            acc[c] = __builtin_amdgcn_mfma_f32_16x16x32_bf16(af, bf, acc[c], 0, 0, 0);
        }
    }

#pragma unroll
    for (int c = 0; c < 4; c++) {
#pragma unroll
        for (int reg = 0; reg < 4; reg++) {
            int row = quad * 4 + reg;
            int gm = m0 + wave * 16 + row;
            if (gm < cnt) {
                int gn = n0 + c * 16 + l16;
                float v = acc[c][reg] + b1[e * H_DIM + gn];
                v = 0.5f * v * (1.f + erff(v * 0.70710678118654752f));  // exact-erf GELU
                h[(size_t)(off + gm) * H_DIM + gn] = f2bf(v);
            }
        }
    }
}

// ---------------- FFN layer 2: out += cw * (h @ w2[e]^T + b2[e]) ----------------
__global__ __launch_bounds__(256) void ffn2_kernel(
    const ushort* __restrict__ h, const float* __restrict__ w2, const float* __restrict__ b2,
    const int* __restrict__ counts, const int* __restrict__ offsets,
    const int* __restrict__ pair_token, const float* __restrict__ pair_w,
    float* __restrict__ out)
{
    int e = blockIdx.z;
    int cnt = counts[e];
    int m0 = blockIdx.x * 64;
    if (m0 >= cnt) return;
    int off = offsets[e];
    int n0 = blockIdx.y * 64;

    __shared__ ushort As[64][40];
    __shared__ ushort Bs[64][40];

    int tid = threadIdx.x;
    int r = tid >> 2, cseg = (tid & 3) * 8;
    int gr = m0 + r; if (gr > cnt - 1) gr = cnt - 1;
    const ushort* arow = h + (size_t)(off + gr) * H_DIM + cseg;
    const float* brow = w2 + ((size_t)e * D_DIM + n0 + r) * H_DIM + cseg;

    int wave = tid >> 6, lane = tid & 63;
    int quad = lane >> 4, l16 = lane & 15;

    floatx4 acc[4] = {};
    const short8* aF = (const short8*)&As[wave * 16 + l16][quad * 8];

    for (int k0 = 0; k0 < H_DIM; k0 += 32) {
        uint4 av = *(const uint4*)(arow + k0);          // h already bf16
        float4 b0 = *(const float4*)(brow + k0);
        float4 b1v = *(const float4*)(brow + k0 + 4);
        __syncthreads();
        *(uint4*)&As[r][cseg] = av;
        *(uint4*)&Bs[r][cseg] = pack8(b0, b1v);
        __syncthreads();
        short8 af = *aF;
#pragma unroll
        for (int c = 0; c < 4; c++) {
            short8 bf = *(const short8*)&Bs[c * 16 + l16][quad * 8];
            acc[c] = __builtin_amdgcn_mfma_f32_16x16x32_bf16(af, bf, acc[c], 0, 0, 0);
        }
    }

#pragma unroll
    for (int c = 0; c < 4; c++) {
#pragma unroll
        for (int reg = 0; reg < 4; reg++) {
            int row = quad * 4 + reg;
            int gm = m0 + wave * 16 + row;
            if (gm < cnt) {
                int gn = n0 + c * 16 + l16;
                int tok = pair_token[off + gm];
                float wgt = pair_w[off + gm];
                float v = (acc[c][reg] + b2[e * D_DIM + gn]) * wgt;
                atomicAdd(&out[(size_t)tok * D_DIM + gn], v);
            }
        }
    }
}

extern "C" void kernel_launch(void* const* d_in, const int* in_sizes, int n_in,
                              void* d_out, int out_size, void* d_ws, size_t ws_size,
                              hipStream_t stream)
{
    const float* x  = (const float*)d_in[0];
    const float* rw = (const float*)d_in[1];
    const float* w1 = (const float*)d_in[2];
    const float* b1 = (const float*)d_in[3];
    const float* w2 = (const float*)d_in[4];
    const float* b2 = (const float*)d_in[5];
    float* out = (float*)d_out;

    char* ws = (char*)d_ws;
    int*   counts     = (int*)(ws + 0);
    int*   cursors    = (int*)(ws + 256);
    int*   offsets    = (int*)(ws + 512);
    int*   topi       = (int*)(ws + 1024);                    // 32768 B
    float* topw       = (float*)(ws + 33792);                 // 32768 B
    int*   pair_token = (int*)(ws + 66560);                   // 32768 B
    float* pair_w     = (float*)(ws + 99328);                 // 32768 B
    ushort* h         = (ushort*)(ws + 132096);               // 64 MiB (bf16 [8192 x 4096])

    hipMemsetAsync(counts, 0, 32, stream);
    hipMemsetAsync(out, 0, (size_t)T_TOK * D_DIM * sizeof(float), stream);

    router_kernel<<<T_TOK / 4, 256, 0, stream>>>(x, rw, counts, topi, topw);
    offsets_kernel<<<1, 64, 0, stream>>>(counts, offsets, cursors);
    assign_kernel<<<T_TOK / 256, 256, 0, stream>>>(topi, topw, cursors, pair_token, pair_w);

    dim3 g1(64, H_DIM / 64, E_NUM);
    ffn1_kernel<<<g1, 256, 0, stream>>>(x, w1, b1, counts, offsets, pair_token, h);

    dim3 g2(64, D_DIM / 64, E_NUM);
    ffn2_kernel<<<g2, 256, 0, stream>>>(h, w2, b2, counts, offsets, pair_token, pair_w, out);
}

// Round 3
// 1160.460 us; speedup vs baseline: 1.0640x; 1.0640x over previous
//
#include <hip/hip_runtime.h>
#include <stdint.h>

typedef __attribute__((ext_vector_type(8))) short short8;
typedef __attribute__((ext_vector_type(4))) float floatx4;

#define T_TOK 4096
#define D_DIM 1024
#define H_DIM 4096
#define E_NUM 8

static __device__ __forceinline__ ushort f2bf(float f) {
    uint32_t u = __float_as_uint(f);
    u += 0x7FFF + ((u >> 16) & 1);   // round-to-nearest-even
    return (ushort)(u >> 16);
}

static __device__ __forceinline__ uint4 pack8(float4 a, float4 b) {
    union { ushort u[8]; uint4 v; } r;
    r.u[0] = f2bf(a.x); r.u[1] = f2bf(a.y); r.u[2] = f2bf(a.z); r.u[3] = f2bf(a.w);
    r.u[4] = f2bf(b.x); r.u[5] = f2bf(b.y); r.u[6] = f2bf(b.z); r.u[7] = f2bf(b.w);
    return r.v;
}

// async global->LDS, 16B per lane; LDS dest = wave-uniform base + lane*16
static __device__ __forceinline__ void gl_lds16(const void* g, void* l) {
    __builtin_amdgcn_global_load_lds(
        (const __attribute__((address_space(1))) uint32_t*)g,
        (__attribute__((address_space(3))) uint32_t*)l, 16, 0, 0);
}

// ---------------- f32 -> bf16 bulk convert ----------------
__global__ __launch_bounds__(256) void cvt_kernel(const float* __restrict__ src,
                                                  ushort* __restrict__ dst)
{
    size_t i = ((size_t)blockIdx.x * 256 + threadIdx.x) * 8;
    float4 a = *(const float4*)(src + i);
    float4 b = *(const float4*)(src + i + 4);
    *(uint4*)(dst + i) = pack8(a, b);
}

// ---------------- Router: logits -> softmax -> top2 -> renorm (all f32) ------
__global__ __launch_bounds__(256) void router_kernel(
    const float* __restrict__ x, const float* __restrict__ rw,
    int* __restrict__ counts, int* __restrict__ topi, float* __restrict__ topw)
{
    __shared__ float rwS[E_NUM * D_DIM];             // 32 KB
    int tid = threadIdx.x;
    for (int i = tid; i < E_NUM * D_DIM / 4; i += 256)
        ((float4*)rwS)[i] = ((const float4*)rw)[i];
    __syncthreads();

    int wave = tid >> 6, lane = tid & 63;
    int t = blockIdx.x * 4 + wave;
    const float* xr = x + (size_t)t * D_DIM;

    float acc[E_NUM];
#pragma unroll
    for (int e = 0; e < E_NUM; e++) acc[e] = 0.f;

    float xv[16];
#pragma unroll
    for (int j = 0; j < 4; j++)
        *(float4*)&xv[j * 4] = ((const float4*)xr)[lane * 4 + j];
#pragma unroll
    for (int j = 0; j < 16; j++) {
        int idx = lane * 16 + j;
#pragma unroll
        for (int e = 0; e < E_NUM; e++)
            acc[e] += xv[j] * rwS[e * D_DIM + idx];
    }
#pragma unroll
    for (int e = 0; e < E_NUM; e++)
        for (int off = 32; off > 0; off >>= 1)
            acc[e] += __shfl_xor(acc[e], off, 64);

    if (lane == 0) {
        float mx = acc[0];
        for (int e = 1; e < E_NUM; e++) mx = fmaxf(mx, acc[e]);
        float p[E_NUM];
        for (int e = 0; e < E_NUM; e++) p[e] = expf(acc[e] - mx);
        int i0 = 0;
        for (int e = 1; e < E_NUM; e++) if (p[e] > p[i0]) i0 = e;   // lowest-idx tie-break
        int i1 = (i0 == 0) ? 1 : 0;
        for (int e = 0; e < E_NUM; e++) if (e != i0 && p[e] > p[i1]) i1 = e;
        float w0 = p[i0], w1 = p[i1], sw = w0 + w1;
        w0 /= sw; w1 /= sw;
        topi[t * 2] = i0; topi[t * 2 + 1] = i1;
        topw[t * 2] = w0; topw[t * 2 + 1] = w1;
        atomicAdd(&counts[i0], 1);
        atomicAdd(&counts[i1], 1);
    }
}

__global__ void offsets_kernel(const int* __restrict__ counts,
                               int* __restrict__ offsets, int* __restrict__ cursors)
{
    if (threadIdx.x == 0 && blockIdx.x == 0) {
        int off = 0;
        for (int e = 0; e < E_NUM; e++) {
            offsets[e] = off; cursors[e] = off; off += counts[e];
        }
    }
}

__global__ __launch_bounds__(256) void assign_kernel(
    const int* __restrict__ topi, const float* __restrict__ topw,
    int* __restrict__ cursors, int* __restrict__ pair_token, float* __restrict__ pair_w,
    int* __restrict__ ppos)
{
    int t = blockIdx.x * 256 + threadIdx.x;
    if (t >= T_TOK) return;
    for (int k = 0; k < 2; k++) {
        int e = topi[t * 2 + k];
        int pos = atomicAdd(&cursors[e], 1);
        pair_token[pos] = t;
        pair_w[pos] = topw[t * 2 + k];
        ppos[t * 2 + k] = pos;
    }
}

// ---------------- FFN layer 1: h = gelu(xbf @ w1bf^T + b1) -------------------
// 128x128 tile, BK=32, 4 waves in 2x2, 4x4 16x16x32 MFMA frags per wave.
// A/B staged via global_load_lds(16B); LDS layout [128 rows][4 x 16B blocks],
// block index XOR-swizzled by (row>>1)&3 -> conflict-free b128 frag reads.
__global__ __launch_bounds__(256) void ffn1_kernel(
    const ushort* __restrict__ xbf, const ushort* __restrict__ w1bf,
    const float* __restrict__ bias1,
    const int* __restrict__ counts, const int* __restrict__ offsets,
    const int* __restrict__ pair_token, ushort* __restrict__ h)
{
    int e = blockIdx.z;
    int cnt = counts[e];
    int m0 = blockIdx.x * 128;
    if (m0 >= cnt) return;
    int off = offsets[e];
    int n0 = blockIdx.y * 128;

    __shared__ ushort As[128 * 32];   // 8 KB
    __shared__ ushort Bs[128 * 32];   // 8 KB

    const int t = threadIdx.x;
    const int wave = t >> 6, lane = t & 63;
    const int wm = (wave >> 1) * 64, wn = (wave & 1) * 64;
    const int quad = lane >> 4, l16 = lane & 15;

    // staging mapping: thread t handles chunk t (rows 0..63) and t+256 (rows 64..127)
    const int r0 = t >> 2;
    const int jb = t & 3;
    const int s0 = (r0 >> 1) & 3;
    const int csrc = (jb ^ s0) * 8;         // source col offset (elems)

    int grA0 = m0 + r0;        if (grA0 >= cnt) grA0 = cnt - 1;
    int grA1 = m0 + r0 + 64;   if (grA1 >= cnt) grA1 = cnt - 1;
    const ushort* aS0 = xbf + (size_t)pair_token[off + grA0] * D_DIM + csrc;
    const ushort* aS1 = xbf + (size_t)pair_token[off + grA1] * D_DIM + csrc;
    const ushort* bS0 = w1bf + ((size_t)e * H_DIM + n0 + r0) * D_DIM + csrc;
    const ushort* bS1 = bS0 + (size_t)64 * D_DIM;

    char* AsB = (char*)As;
    char* BsB = (char*)Bs;
    const int ldsW = wave * 1024;           // per-wave dest base within 4096B segment

    // fragment LDS byte offsets (row*64 + swizzled-block*16)
    const int swz = (((l16 >> 1) & 3) ^ quad) * 16;
    int aOff[4], bOff[4];
#pragma unroll
    for (int i = 0; i < 4; i++) {
        aOff[i] = (wm + i * 16 + l16) * 64 + swz;
        bOff[i] = (wn + i * 16 + l16) * 64 + swz;
    }

    floatx4 acc[4][4] = {};

    for (int k0 = 0; k0 < D_DIM; k0 += 32) {
        __syncthreads();                     // prior tile reads done
        gl_lds16(aS0 + k0, AsB + ldsW);
        gl_lds16(aS1 + k0, AsB + 4096 + ldsW);
        gl_lds16(bS0 + k0, BsB + ldsW);
        gl_lds16(bS1 + k0, BsB + 4096 + ldsW);
        __syncthreads();                     // staging drained (vmcnt(0) before barrier)

        short8 av[4], bv[4];
#pragma unroll
        for (int i = 0; i < 4; i++) av[i] = *(const short8*)(AsB + aOff[i]);
#pragma unroll
        for (int i = 0; i < 4; i++) bv[i] = *(const short8*)(BsB + bOff[i]);
#pragma unroll
        for (int mi = 0; mi < 4; mi++)
#pragma unroll
            for (int ni = 0; ni < 4; ni++)
                acc[mi][ni] = __builtin_amdgcn_mfma_f32_16x16x32_bf16(av[mi], bv[ni], acc[mi][ni], 0, 0, 0);
    }

    float bb[4];
#pragma unroll
    for (int ni = 0; ni < 4; ni++) bb[ni] = bias1[e * H_DIM + n0 + wn + ni * 16 + l16];

#pragma unroll
    for (int mi = 0; mi < 4; mi++) {
#pragma unroll
        for (int reg = 0; reg < 4; reg++) {
            int gm = m0 + wm + mi * 16 + quad * 4 + reg;
            if (gm < cnt) {
                ushort* hrow = h + (size_t)(off + gm) * H_DIM + n0 + wn;
#pragma unroll
                for (int ni = 0; ni < 4; ni++) {
                    float v = acc[mi][ni][reg] + bb[ni];
                    v = 0.5f * v * (1.f + erff(v * 0.70710678118654752f));
                    hrow[ni * 16 + l16] = f2bf(v);
                }
            }
        }
    }
}

// ---------------- FFN layer 2: o_pair = cw * (h @ w2bf^T + b2) ---------------
__global__ __launch_bounds__(256) void ffn2_kernel(
    const ushort* __restrict__ h, const ushort* __restrict__ w2bf,
    const float* __restrict__ bias2,
    const int* __restrict__ counts, const int* __restrict__ offsets,
    const float* __restrict__ pair_w, float* __restrict__ o_pair)
{
    int e = blockIdx.z;
    int cnt = counts[e];
    int m0 = blockIdx.x * 128;
    if (m0 >= cnt) return;
    int off = offsets[e];
    int n0 = blockIdx.y * 128;

    __shared__ ushort As[128 * 32];
    __shared__ ushort Bs[128 * 32];

    const int t = threadIdx.x;
    const int wave = t >> 6, lane = t & 63;
    const int wm = (wave >> 1) * 64, wn = (wave & 1) * 64;
    const int quad = lane >> 4, l16 = lane & 15;

    const int r0 = t >> 2;
    const int jb = t & 3;
    const int s0 = (r0 >> 1) & 3;
    const int csrc = (jb ^ s0) * 8;

    int grA0 = m0 + r0;        if (grA0 >= cnt) grA0 = cnt - 1;
    int grA1 = m0 + r0 + 64;   if (grA1 >= cnt) grA1 = cnt - 1;
    const ushort* aS0 = h + (size_t)(off + grA0) * H_DIM + csrc;
    const ushort* aS1 = h + (size_t)(off + grA1) * H_DIM + csrc;
    const ushort* bS0 = w2bf + ((size_t)e * D_DIM + n0 + r0) * H_DIM + csrc;
    const ushort* bS1 = bS0 + (size_t)64 * H_DIM;

    char* AsB = (char*)As;
    char* BsB = (char*)Bs;
    const int ldsW = wave * 1024;

    const int swz = (((l16 >> 1) & 3) ^ quad) * 16;
    int aOff[4], bOff[4];
#pragma unroll
    for (int i = 0; i < 4; i++) {
        aOff[i] = (wm + i * 16 + l16) * 64 + swz;
        bOff[i] = (wn + i * 16 + l16) * 64 + swz;
    }

    floatx4 acc[4][4] = {};

    for (int k0 = 0; k0 < H_DIM; k0 += 32) {
        __syncthreads();
        gl_lds16(aS0 + k0, AsB + ldsW);
        gl_lds16(aS1 + k0, AsB + 4096 + ldsW);
        gl_lds16(bS0 + k0, BsB + ldsW);
        gl_lds16(bS1 + k0, BsB + 4096 + ldsW);
        __syncthreads();

        short8 av[4], bv[4];
#pragma unroll
        for (int i = 0; i < 4; i++) av[i] = *(const short8*)(AsB + aOff[i]);
#pragma unroll
        for (int i = 0; i < 4; i++) bv[i] = *(const short8*)(BsB + bOff[i]);
#pragma unroll
        for (int mi = 0; mi < 4; mi++)
#pragma unroll
            for (int ni = 0; ni < 4; ni++)
                acc[mi][ni] = __builtin_amdgcn_mfma_f32_16x16x32_bf16(av[mi], bv[ni], acc[mi][ni], 0, 0, 0);
    }

    float bb[4];
#pragma unroll
    for (int ni = 0; ni < 4; ni++) bb[ni] = bias2[e * D_DIM + n0 + wn + ni * 16 + l16];

#pragma unroll
    for (int mi = 0; mi < 4; mi++) {
#pragma unroll
        for (int reg = 0; reg < 4; reg++) {
            int gm = m0 + wm + mi * 16 + quad * 4 + reg;
            if (gm < cnt) {
                float wgt = pair_w[off + gm];
                float* orow = o_pair + (size_t)(off + gm) * D_DIM + n0 + wn;
#pragma unroll
                for (int ni = 0; ni < 4; ni++)
                    orow[ni * 16 + l16] = (acc[mi][ni][reg] + bb[ni]) * wgt;
            }
        }
    }
}

// ---------------- combine: out[t] = o_pair[pos0] + o_pair[pos1] --------------
__global__ __launch_bounds__(256) void combine_kernel(
    const float* __restrict__ o_pair, const int* __restrict__ ppos,
    float* __restrict__ out)
{
    int t = blockIdx.x;
    int d = threadIdx.x * 4;
    size_t p0 = (size_t)ppos[t * 2] * D_DIM;
    size_t p1 = (size_t)ppos[t * 2 + 1] * D_DIM;
    float4 a = *(const float4*)(o_pair + p0 + d);
    float4 b = *(const float4*)(o_pair + p1 + d);
    float4 r;
    r.x = a.x + b.x; r.y = a.y + b.y; r.z = a.z + b.z; r.w = a.w + b.w;
    *(float4*)(out + (size_t)t * D_DIM + d) = r;
}

extern "C" void kernel_launch(void* const* d_in, const int* in_sizes, int n_in,
                              void* d_out, int out_size, void* d_ws, size_t ws_size,
                              hipStream_t stream)
{
    const float* x  = (const float*)d_in[0];
    const float* rw = (const float*)d_in[1];
    const float* w1 = (const float*)d_in[2];
    const float* b1 = (const float*)d_in[3];
    const float* w2 = (const float*)d_in[4];
    const float* b2 = (const float*)d_in[5];
    float* out = (float*)d_out;

    char* ws = (char*)d_ws;
    int*   counts     = (int*)(ws + 0);
    int*   cursors    = (int*)(ws + 256);
    int*   offsets    = (int*)(ws + 512);
    int*   topi       = (int*)(ws + 1024);
    float* topw       = (float*)(ws + 33792);
    int*   pair_token = (int*)(ws + 66560);
    float* pair_w     = (float*)(ws + 99328);
    int*   ppos       = (int*)(ws + 132096);
    ushort* xbf  = (ushort*)(ws + 165888);                        // 8 MiB
    ushort* w1bf = (ushort*)(ws + 8554496ULL);                    // 64 MiB
    ushort* w2bf = (ushort*)(ws + 75663360ULL);                   // 64 MiB
    ushort* h    = (ushort*)(ws + 142772224ULL);                  // 64 MiB
    float* o_pair = (float*)(ws + 8554496ULL);                    // 32 MiB, overlays w1bf (dead after ffn1)

    hipMemsetAsync(counts, 0, 32, stream);

    cvt_kernel<<<(T_TOK * D_DIM) / 2048, 256, 0, stream>>>(x, xbf);
    cvt_kernel<<<(E_NUM * H_DIM * D_DIM) / 2048, 256, 0, stream>>>(w1, w1bf);
    cvt_kernel<<<(E_NUM * D_DIM * H_DIM) / 2048, 256, 0, stream>>>(w2, w2bf);

    router_kernel<<<T_TOK / 4, 256, 0, stream>>>(x, rw, counts, topi, topw);
    offsets_kernel<<<1, 64, 0, stream>>>(counts, offsets, cursors);
    assign_kernel<<<T_TOK / 256, 256, 0, stream>>>(topi, topw, cursors, pair_token, pair_w, ppos);

    dim3 g1(T_TOK * 2 / 128, H_DIM / 128, E_NUM);
    ffn1_kernel<<<g1, 256, 0, stream>>>(xbf, w1bf, b1, counts, offsets, pair_token, h);

    dim3 g2(T_TOK * 2 / 128, D_DIM / 128, E_NUM);
    ffn2_kernel<<<g2, 256, 0, stream>>>(h, w2bf, b2, counts, offsets, pair_w, o_pair);

    combine_kernel<<<T_TOK, 256, 0, stream>>>(o_pair, ppos, out);
}

// Round 4
// 814.878 us; speedup vs baseline: 1.5152x; 1.4241x over previous
//
#include <hip/hip_runtime.h>
#include <stdint.h>

typedef __attribute__((ext_vector_type(8))) short short8;
typedef __attribute__((ext_vector_type(4))) float floatx4;

#define T_TOK 4096
#define D_DIM 1024
#define H_DIM 4096
#define E_NUM 8
#define MAX_TILES 71   // sum_e ceil(cnt_e/128) <= 8192/128 + 7

static __device__ __forceinline__ ushort f2bf(float f) {
    uint32_t u = __float_as_uint(f);
    u += 0x7FFF + ((u >> 16) & 1);   // round-to-nearest-even
    return (ushort)(u >> 16);
}

static __device__ __forceinline__ uint4 pack8(float4 a, float4 b) {
    union { ushort u[8]; uint4 v; } r;
    r.u[0] = f2bf(a.x); r.u[1] = f2bf(a.y); r.u[2] = f2bf(a.z); r.u[3] = f2bf(a.w);
    r.u[4] = f2bf(b.x); r.u[5] = f2bf(b.y); r.u[6] = f2bf(b.z); r.u[7] = f2bf(b.w);
    return r.v;
}

// async global->LDS, 16B per lane; LDS dest = wave-uniform base + lane*16
static __device__ __forceinline__ void gl_lds16(const void* g, void* l) {
    __builtin_amdgcn_global_load_lds(
        (const __attribute__((address_space(1))) uint32_t*)g,
        (__attribute__((address_space(3))) uint32_t*)l, 16, 0, 0);
}

// ---------------- fused f32 -> bf16 bulk convert (x, w1, w2 in one grid) -----
__global__ __launch_bounds__(256) void cvt_all_kernel(
    const float* __restrict__ x,  ushort* __restrict__ xbf,
    const float* __restrict__ w1, ushort* __restrict__ w1bf,
    const float* __restrict__ w2, ushort* __restrict__ w2bf)
{
    const size_t NX = (size_t)T_TOK * D_DIM;            // 4M
    const size_t NW = (size_t)E_NUM * H_DIM * D_DIM;    // 32M
    size_t i = ((size_t)blockIdx.x * 256 + threadIdx.x) * 8;
    const float* src; ushort* dst; size_t j;
    if (i < NX)           { src = x;  dst = xbf;  j = i; }
    else if (i < NX + NW) { src = w1; dst = w1bf; j = i - NX; }
    else                  { src = w2; dst = w2bf; j = i - NX - NW; }
    float4 a = *(const float4*)(src + j);
    float4 b = *(const float4*)(src + j + 4);
    *(uint4*)(dst + j) = pack8(a, b);
}

// ---------------- Router: logits -> softmax -> top2 -> renorm (all f32) ------
__global__ __launch_bounds__(256) void router_kernel(
    const float* __restrict__ x, const float* __restrict__ rw,
    int* __restrict__ counts, int* __restrict__ topi, float* __restrict__ topw)
{
    __shared__ float rwS[E_NUM * D_DIM];             // 32 KB
    int tid = threadIdx.x;
    for (int i = tid; i < E_NUM * D_DIM / 4; i += 256)
        ((float4*)rwS)[i] = ((const float4*)rw)[i];
    __syncthreads();

    int wave = tid >> 6, lane = tid & 63;
    int t = blockIdx.x * 4 + wave;
    const float* xr = x + (size_t)t * D_DIM;

    float acc[E_NUM];
#pragma unroll
    for (int e = 0; e < E_NUM; e++) acc[e] = 0.f;

    float xv[16];
#pragma unroll
    for (int j = 0; j < 4; j++)
        *(float4*)&xv[j * 4] = ((const float4*)xr)[lane * 4 + j];
#pragma unroll
    for (int j = 0; j < 16; j++) {
        int idx = lane * 16 + j;
#pragma unroll
        for (int e = 0; e < E_NUM; e++)
            acc[e] += xv[j] * rwS[e * D_DIM + idx];
    }
#pragma unroll
    for (int e = 0; e < E_NUM; e++)
        for (int off = 32; off > 0; off >>= 1)
            acc[e] += __shfl_xor(acc[e], off, 64);

    if (lane == 0) {
        float mx = acc[0];
        for (int e = 1; e < E_NUM; e++) mx = fmaxf(mx, acc[e]);
        float p[E_NUM];
        for (int e = 0; e < E_NUM; e++) p[e] = expf(acc[e] - mx);
        int i0 = 0;
        for (int e = 1; e < E_NUM; e++) if (p[e] > p[i0]) i0 = e;   // lowest-idx tie-break
        int i1 = (i0 == 0) ? 1 : 0;
        for (int e = 0; e < E_NUM; e++) if (e != i0 && p[e] > p[i1]) i1 = e;
        float w0 = p[i0], w1 = p[i1], sw = w0 + w1;
        w0 /= sw; w1 /= sw;
        topi[t * 2] = i0; topi[t * 2 + 1] = i1;
        topw[t * 2] = w0; topw[t * 2 + 1] = w1;
        atomicAdd(&counts[i0], 1);
        atomicAdd(&counts[i1], 1);
    }
}

// offsets + exact tile list (kills dead blocks in the GEMM grids)
__global__ void offsets_tiles_kernel(const int* __restrict__ counts,
                                     int* __restrict__ offsets, int* __restrict__ cursors,
                                     int* __restrict__ tile_e, int* __restrict__ tile_m0)
{
    if (threadIdx.x == 0 && blockIdx.x == 0) {
        int off = 0, n = 0;
        for (int e = 0; e < E_NUM; e++) {
            offsets[e] = off; cursors[e] = off; off += counts[e];
            for (int m0 = 0; m0 < counts[e]; m0 += 128) {
                tile_e[n] = e; tile_m0[n] = m0; n++;
            }
        }
        for (; n < MAX_TILES; n++) tile_e[n] = -1;
    }
}

__global__ __launch_bounds__(256) void assign_kernel(
    const int* __restrict__ topi, const float* __restrict__ topw,
    int* __restrict__ cursors, int* __restrict__ pair_token, float* __restrict__ pair_w,
    int* __restrict__ ppos)
{
    int t = blockIdx.x * 256 + threadIdx.x;
    if (t >= T_TOK) return;
    for (int k = 0; k < 2; k++) {
        int e = topi[t * 2 + k];
        int pos = atomicAdd(&cursors[e], 1);
        pair_token[pos] = t;
        pair_w[pos] = topw[t * 2 + k];
        ppos[t * 2 + k] = pos;
    }
}

// ---------------- FFN layer 1: h = gelu(xbf @ w1bf^T + b1) -------------------
// 128x128 tile, BK=32, 4 waves 2x2, 4x4 16x16x32 MFMA frags; tile-list grid.
__global__ __launch_bounds__(256) void ffn1_kernel(
    const ushort* __restrict__ xbf, const ushort* __restrict__ w1bf,
    const float* __restrict__ bias1,
    const int* __restrict__ counts, const int* __restrict__ offsets,
    const int* __restrict__ tile_e, const int* __restrict__ tile_m0,
    const int* __restrict__ pair_token, ushort* __restrict__ h)
{
    int e = tile_e[blockIdx.x];
    if (e < 0) return;
    int m0 = tile_m0[blockIdx.x];
    int cnt = counts[e];
    int off = offsets[e];
    int n0 = blockIdx.y * 128;

    __shared__ ushort As[128 * 32];   // 8 KB
    __shared__ ushort Bs[128 * 32];   // 8 KB

    const int t = threadIdx.x;
    const int wave = t >> 6, lane = t & 63;
    const int wm = (wave >> 1) * 64, wn = (wave & 1) * 64;
    const int quad = lane >> 4, l16 = lane & 15;

    const int r0 = t >> 2;
    const int jb = t & 3;
    const int s0 = (r0 >> 1) & 3;
    const int csrc = (jb ^ s0) * 8;         // XOR-swizzled source col offset

    int grA0 = m0 + r0;        if (grA0 >= cnt) grA0 = cnt - 1;
    int grA1 = m0 + r0 + 64;   if (grA1 >= cnt) grA1 = cnt - 1;
    const ushort* aS0 = xbf + (size_t)pair_token[off + grA0] * D_DIM + csrc;
    const ushort* aS1 = xbf + (size_t)pair_token[off + grA1] * D_DIM + csrc;
    const ushort* bS0 = w1bf + ((size_t)e * H_DIM + n0 + r0) * D_DIM + csrc;
    const ushort* bS1 = bS0 + (size_t)64 * D_DIM;

    char* AsB = (char*)As;
    char* BsB = (char*)Bs;
    const int ldsW = wave * 1024;

    const int swz = (((l16 >> 1) & 3) ^ quad) * 16;
    int aOff[4], bOff[4];
#pragma unroll
    for (int i = 0; i < 4; i++) {
        aOff[i] = (wm + i * 16 + l16) * 64 + swz;
        bOff[i] = (wn + i * 16 + l16) * 64 + swz;
    }

    floatx4 acc[4][4] = {};

    for (int k0 = 0; k0 < D_DIM; k0 += 32) {
        __syncthreads();
        gl_lds16(aS0 + k0, AsB + ldsW);
        gl_lds16(aS1 + k0, AsB + 4096 + ldsW);
        gl_lds16(bS0 + k0, BsB + ldsW);
        gl_lds16(bS1 + k0, BsB + 4096 + ldsW);
        __syncthreads();

        short8 av[4], bv[4];
#pragma unroll
        for (int i = 0; i < 4; i++) av[i] = *(const short8*)(AsB + aOff[i]);
#pragma unroll
        for (int i = 0; i < 4; i++) bv[i] = *(const short8*)(BsB + bOff[i]);
#pragma unroll
        for (int mi = 0; mi < 4; mi++)
#pragma unroll
            for (int ni = 0; ni < 4; ni++)
                acc[mi][ni] = __builtin_amdgcn_mfma_f32_16x16x32_bf16(av[mi], bv[ni], acc[mi][ni], 0, 0, 0);
    }

    float bb[4];
#pragma unroll
    for (int ni = 0; ni < 4; ni++) bb[ni] = bias1[e * H_DIM + n0 + wn + ni * 16 + l16];

#pragma unroll
    for (int mi = 0; mi < 4; mi++) {
#pragma unroll
        for (int reg = 0; reg < 4; reg++) {
            int gm = m0 + wm + mi * 16 + quad * 4 + reg;
            if (gm < cnt) {
                ushort* hrow = h + (size_t)(off + gm) * H_DIM + n0 + wn;
#pragma unroll
                for (int ni = 0; ni < 4; ni++) {
                    float v = acc[mi][ni][reg] + bb[ni];
                    v = 0.5f * v * (1.f + erff(v * 0.70710678118654752f));
                    hrow[ni * 16 + l16] = f2bf(v);
                }
            }
        }
    }
}

// ---------------- FFN layer 2: o_pair = cw * (h @ w2bf^T + b2) ---------------
__global__ __launch_bounds__(256) void ffn2_kernel(
    const ushort* __restrict__ h, const ushort* __restrict__ w2bf,
    const float* __restrict__ bias2,
    const int* __restrict__ counts, const int* __restrict__ offsets,
    const int* __restrict__ tile_e, const int* __restrict__ tile_m0,
    const float* __restrict__ pair_w, float* __restrict__ o_pair)
{
    int e = tile_e[blockIdx.x];
    if (e < 0) return;
    int m0 = tile_m0[blockIdx.x];
    int cnt = counts[e];
    int off = offsets[e];
    int n0 = blockIdx.y * 128;

    __shared__ ushort As[128 * 32];
    __shared__ ushort Bs[128 * 32];

    const int t = threadIdx.x;
    const int wave = t >> 6, lane = t & 63;
    const int wm = (wave >> 1) * 64, wn = (wave & 1) * 64;
    const int quad = lane >> 4, l16 = lane & 15;

    const int r0 = t >> 2;
    const int jb = t & 3;
    const int s0 = (r0 >> 1) & 3;
    const int csrc = (jb ^ s0) * 8;

    int grA0 = m0 + r0;        if (grA0 >= cnt) grA0 = cnt - 1;
    int grA1 = m0 + r0 + 64;   if (grA1 >= cnt) grA1 = cnt - 1;
    const ushort* aS0 = h + (size_t)(off + grA0) * H_DIM + csrc;
    const ushort* aS1 = h + (size_t)(off + grA1) * H_DIM + csrc;
    const ushort* bS0 = w2bf + ((size_t)e * D_DIM + n0 + r0) * H_DIM + csrc;
    const ushort* bS1 = bS0 + (size_t)64 * H_DIM;

    char* AsB = (char*)As;
    char* BsB = (char*)Bs;
    const int ldsW = wave * 1024;

    const int swz = (((l16 >> 1) & 3) ^ quad) * 16;
    int aOff[4], bOff[4];
#pragma unroll
    for (int i = 0; i < 4; i++) {
        aOff[i] = (wm + i * 16 + l16) * 64 + swz;
        bOff[i] = (wn + i * 16 + l16) * 64 + swz;
    }

    floatx4 acc[4][4] = {};

    for (int k0 = 0; k0 < H_DIM; k0 += 32) {
        __syncthreads();
        gl_lds16(aS0 + k0, AsB + ldsW);
        gl_lds16(aS1 + k0, AsB + 4096 + ldsW);
        gl_lds16(bS0 + k0, BsB + ldsW);
        gl_lds16(bS1 + k0, BsB + 4096 + ldsW);
        __syncthreads();

        short8 av[4], bv[4];
#pragma unroll
        for (int i = 0; i < 4; i++) av[i] = *(const short8*)(AsB + aOff[i]);
#pragma unroll
        for (int i = 0; i < 4; i++) bv[i] = *(const short8*)(BsB + bOff[i]);
#pragma unroll
        for (int mi = 0; mi < 4; mi++)
#pragma unroll
            for (int ni = 0; ni < 4; ni++)
                acc[mi][ni] = __builtin_amdgcn_mfma_f32_16x16x32_bf16(av[mi], bv[ni], acc[mi][ni], 0, 0, 0);
    }

    float bb[4];
#pragma unroll
    for (int ni = 0; ni < 4; ni++) bb[ni] = bias2[e * D_DIM + n0 + wn + ni * 16 + l16];

#pragma unroll
    for (int mi = 0; mi < 4; mi++) {
#pragma unroll
        for (int reg = 0; reg < 4; reg++) {
            int gm = m0 + wm + mi * 16 + quad * 4 + reg;
            if (gm < cnt) {
                float wgt = pair_w[off + gm];
                float* orow = o_pair + (size_t)(off + gm) * D_DIM + n0 + wn;
#pragma unroll
                for (int ni = 0; ni < 4; ni++)
                    orow[ni * 16 + l16] = (acc[mi][ni][reg] + bb[ni]) * wgt;
            }
        }
    }
}

// ---------------- combine: out[t] = o_pair[pos0] + o_pair[pos1] --------------
__global__ __launch_bounds__(256) void combine_kernel(
    const float* __restrict__ o_pair, const int* __restrict__ ppos,
    float* __restrict__ out)
{
    int t = blockIdx.x;
    int d = threadIdx.x * 4;
    size_t p0 = (size_t)ppos[t * 2] * D_DIM;
    size_t p1 = (size_t)ppos[t * 2 + 1] * D_DIM;
    float4 a = *(const float4*)(o_pair + p0 + d);
    float4 b = *(const float4*)(o_pair + p1 + d);
    float4 r;
    r.x = a.x + b.x; r.y = a.y + b.y; r.z = a.z + b.z; r.w = a.w + b.w;
    *(float4*)(out + (size_t)t * D_DIM + d) = r;
}

extern "C" void kernel_launch(void* const* d_in, const int* in_sizes, int n_in,
                              void* d_out, int out_size, void* d_ws, size_t ws_size,
                              hipStream_t stream)
{
    const float* x  = (const float*)d_in[0];
    const float* rw = (const float*)d_in[1];
    const float* w1 = (const float*)d_in[2];
    const float* b1 = (const float*)d_in[3];
    const float* w2 = (const float*)d_in[4];
    const float* b2 = (const float*)d_in[5];
    float* out = (float*)d_out;

    char* ws = (char*)d_ws;
    int*   counts     = (int*)(ws + 0);
    int*   cursors    = (int*)(ws + 256);
    int*   offsets    = (int*)(ws + 512);
    int*   tile_e     = (int*)(ws + 1024);
    int*   tile_m0    = (int*)(ws + 1536);
    int*   topi       = (int*)(ws + 2048);
    float* topw       = (float*)(ws + 34816);
    int*   pair_token = (int*)(ws + 67584);
    float* pair_w     = (float*)(ws + 100352);
    int*   ppos       = (int*)(ws + 133120);
    ushort* xbf  = (ushort*)(ws + 165888);                        // 8 MiB
    ushort* w1bf = (ushort*)(ws + 8554496ULL);                    // 64 MiB
    ushort* w2bf = (ushort*)(ws + 75663360ULL);                   // 64 MiB
    ushort* h    = (ushort*)(ws + 142772224ULL);                  // 64 MiB
    float* o_pair = (float*)(ws + 8554496ULL);                    // 32 MiB, overlays w1bf (dead after ffn1)

    hipMemsetAsync(counts, 0, 32, stream);

    const size_t NTOT = (size_t)T_TOK * D_DIM + 2ULL * E_NUM * H_DIM * D_DIM;  // 68M elems
    cvt_all_kernel<<<NTOT / 2048, 256, 0, stream>>>(x, xbf, w1, w1bf, w2, w2bf);

    router_kernel<<<T_TOK / 4, 256, 0, stream>>>(x, rw, counts, topi, topw);
    offsets_tiles_kernel<<<1, 64, 0, stream>>>(counts, offsets, cursors, tile_e, tile_m0);
    assign_kernel<<<T_TOK / 256, 256, 0, stream>>>(topi, topw, cursors, pair_token, pair_w, ppos);

    dim3 g1(MAX_TILES, H_DIM / 128, 1);
    ffn1_kernel<<<g1, 256, 0, stream>>>(xbf, w1bf, b1, counts, offsets, tile_e, tile_m0, pair_token, h);

    dim3 g2(MAX_TILES, D_DIM / 128, 1);
    ffn2_kernel<<<g2, 256, 0, stream>>>(h, w2bf, b2, counts, offsets, tile_e, tile_m0, pair_w, o_pair);

    combine_kernel<<<T_TOK, 256, 0, stream>>>(o_pair, ppos, out);
}